// Round 11
// baseline (252.331 us; speedup 1.0000x reference)
//
#include <hip/hip_runtime.h>
#include <hip/hip_fp16.h>
#include <cstdint>

// Problem constants (match reference)
constexpr int N_NODES = 100000;
constexpr int E_EDGES = 1600000;
constexpr float NEG_SLOPE = 0.2f;
constexpr float INV_TEMP = 1.0f / 0.7f;

// Bucket geometry (global 64-node buckets; record {s | (d&63)<<17, w},
// bucket id d>>6 carried in a side ushort array).
constexpr int BKT_NODES = 64;
constexpr int NBKT = (N_NODES + BKT_NODES - 1) / BKT_NODES;  // 1563
constexpr int REG_B = 1792;                      // recs per bucket (mean 1024, +24 sigma)
constexpr int NR = REG_B / 256;                  // 7 recs held per thread
constexpr int THALF = 2048;                      // R11: 2048 edges/tile -> grid 782
constexpr int NTH = (E_EDGES + THALF - 1) / THALF;  // 782
constexpr int HBINS = 1792;                      // 7*256 scan bins (1563 used)

constexpr int MLP_B = 2;
constexpr int MLP_T = E_EDGES / MLP_B;           // 800000

constexpr int UV_TILE = 64;
constexpr int UV_GRID = (N_NODES + UV_TILE - 1) / UV_TILE;  // 1563

// Workspace offsets -- ALL 128B-aligned (R9 lesson: cacheline-phase shifts
// from geometry changes cost k_mlp 1.5x FETCH; statically pinned since).
constexpr size_t OFF_W2H  = 6272;                               // gcur: NBKT*4=6252
constexpr size_t OFF_RECS = 6400;
constexpr size_t OFF_ASRC = OFF_RECS + (size_t)NBKT * REG_B * 8;  // +22,407,168
constexpr size_t OFF_ADST = OFF_ASRC + 800000;
constexpr size_t OFF_XP2  = OFF_ADST + 800000;
constexpr size_t OFF_U    = OFF_XP2 + 12800000;
constexpr size_t OFF_V    = OFF_U + 6400000;
static_assert(OFF_RECS % 128 == 0 && OFF_ASRC % 128 == 0 && OFF_XP2 % 128 == 0 &&
              OFF_U % 128 == 0 && OFF_V % 128 == 0, "alignment");
static_assert((size_t)NBKT * 4 <= OFF_W2H, "gcur overlap");

__device__ __forceinline__ __half2 bits_to_h2(int bits) {
    return *reinterpret_cast<__half2*>(&bits);
}

// packed relu (no __hmax2 in ROCm 7.2 headers; __hgt2 gives packed 1/0 mask)
__device__ __forceinline__ __half2 h2_relu(__half2 a) {
    const __half2 z = __floats2half2_rn(0.f, 0.f);
    return __hmul2(a, __hgt2(a, z));
}

// ---------------------------------------------------------------------------
// K1: per-node transform. xp2[n][c] = half2(head0_c, head1_c); a_src/a_dst
//     dots [N,2] fp32. Fused: zero gcur[1563], pack w2 -> w2h[16].
// ---------------------------------------------------------------------------
__global__ void k_node(const float* __restrict__ x, const float* __restrict__ W,
                       const float* __restrict__ att_src, const float* __restrict__ att_dst,
                       __half2* __restrict__ xp2, float* __restrict__ a_src,
                       float* __restrict__ a_dst, int* __restrict__ gcur,
                       const float* __restrict__ w2, __half2* __restrict__ w2h) {
    int n = blockIdx.x * blockDim.x + threadIdx.x;
    if (blockIdx.x == 0 && threadIdx.x < 16)
        w2h[threadIdx.x] = __floats2half2_rn(w2[2 * threadIdx.x], w2[2 * threadIdx.x + 1]);
    if (n < NBKT) gcur[n] = 0;
    if (n >= N_NODES) return;
    float xi[16];
    const float4* xv = (const float4*)(x + (size_t)n * 16);
    ((float4*)xi)[0] = xv[0];
    ((float4*)xi)[1] = xv[1];
    ((float4*)xi)[2] = xv[2];
    ((float4*)xi)[3] = xv[3];
    float as0 = 0.f, as1 = 0.f, ad0 = 0.f, ad1 = 0.f;
    __half2 hbuf[32];
#pragma unroll
    for (int c = 0; c < 32; c++) {
        float acc0 = 0.f, acc1 = 0.f;
#pragma unroll
        for (int k = 0; k < 16; k++) {
            acc0 += xi[k] * W[k * 64 + c];
            acc1 += xi[k] * W[k * 64 + 32 + c];
        }
        hbuf[c] = __floats2half2_rn(acc0, acc1);
        as0 += acc0 * att_src[c];
        as1 += acc1 * att_src[32 + c];
        ad0 += acc0 * att_dst[c];
        ad1 += acc1 * att_dst[32 + c];
    }
    float4* dst4 = (float4*)(xp2 + (size_t)n * 32);
#pragma unroll
    for (int q = 0; q < 8; q++) dst4[q] = ((float4*)hbuf)[q];
    ((float2*)a_src)[n] = make_float2(as0, as1);
    ((float2*)a_dst)[n] = make_float2(ad0, ad1);
}

// ---------------------------------------------------------------------------
// K2 (k_split) v3: SINGLE edge sweep (12.8 MB total edge reads).
//     One block per 2048-edge tile (grid 782 -> ~3 blocks/CU; R10's 391
//     blocks @60KB LDS left half the machine idle). Records held in
//     REGISTERS (8/thread, statically indexed) while the histogram+scan
//     complete, then scattered once into bucket-grouped LDS and written
//     out as coalesced segments. LDS ~40.7 KB -> 3 blocks/CU.
// ---------------------------------------------------------------------------
__global__ void __launch_bounds__(256) k_split(
        const int* __restrict__ src, const int* __restrict__ dst,
        const float* __restrict__ a_src, const float* __restrict__ a_dst,
        int* __restrict__ gcur, int2* __restrict__ recs_g) {
    __shared__ int2 lrec[THALF];            // 16 KB
    __shared__ unsigned short bkt[THALF];   // 4 KB
    __shared__ int hist[HBINS];             // 7 KB (becomes inclusive scan)
    __shared__ int psum[256];               // 1 KB
    __shared__ int cnt2[NBKT];              // 6.25 KB
    __shared__ int gbase[NBKT];             // 6.25 KB

    int th = blockIdx.x;
    int tid = threadIdx.x;
    int ebase = th * THALF;

    for (int b = tid; b < HBINS; b += 256) hist[b] = 0;
    for (int b = tid; b < NBKT; b += 256) cnt2[b] = 0;
    __syncthreads();

    // single sweep: read src+dst, compute weights, histogram; records in regs
    int rx[2][4], rw[2][4], rb[2][4], nvs[2];
#pragma unroll
    for (int it = 0; it < 2; it++) {
        int e4 = ebase + (it * 256 + tid) * 4;
        int dd[4], ss[4], nv = 0;
        if (e4 + 3 < E_EDGES) {
            int4 d4 = *(const int4*)(dst + e4);
            int4 s4 = *(const int4*)(src + e4);
            dd[0] = d4.x; dd[1] = d4.y; dd[2] = d4.z; dd[3] = d4.w;
            ss[0] = s4.x; ss[1] = s4.y; ss[2] = s4.z; ss[3] = s4.w;
            nv = 4;
        } else if (e4 < E_EDGES) {
            nv = E_EDGES - e4;
            for (int k = 0; k < nv; k++) { dd[k] = dst[e4 + k]; ss[k] = src[e4 + k]; }
        }
        nvs[it] = nv;
#pragma unroll
        for (int k = 0; k < 4; k++) {
            if (k < nv) {
                int d = dd[k], s = ss[k];
                float2 As = ((const float2*)a_src)[s];
                float2 Ad = ((const float2*)a_dst)[d];
                float e0 = As.x + Ad.x; e0 = (e0 > 0.f) ? e0 : NEG_SLOPE * e0;
                float e1 = As.y + Ad.y; e1 = (e1 > 0.f) ? e1 : NEG_SLOPE * e1;
                __half2 hw = __floats2half2_rn(__expf(e0), __expf(e1));
                rx[it][k] = s | ((d & 63) << 17);
                rw[it][k] = *reinterpret_cast<int*>(&hw);
                rb[it][k] = d >> 6;
                atomicAdd(&hist[d >> 6], 1);
            }
        }
    }
    __syncthreads();

    // blocked inclusive scan over HBINS bins, 7 bins/thread, in place
    int loc[7];
    int tsum = 0;
#pragma unroll
    for (int k = 0; k < 7; k++) { loc[k] = hist[tid * 7 + k]; tsum += loc[k]; }
    psum[tid] = tsum;
    __syncthreads();
    for (int off = 1; off < 256; off <<= 1) {
        int v = (tid >= off) ? psum[tid - off] : 0;
        __syncthreads();
        psum[tid] += v;
        __syncthreads();
    }
    {
        int run = psum[tid] - tsum;          // exclusive prefix of this thread
#pragma unroll
        for (int k = 0; k < 7; k++) { run += loc[k]; hist[tid * 7 + k] = run; }
    }
    __syncthreads();

    // reserve global space (skip empty buckets)
    for (int b = tid; b < NBKT; b += 256) {
        int c = hist[b] - ((b > 0) ? hist[b - 1] : 0);
        gbase[b] = c ? atomicAdd(&gcur[b], c) : 0;
    }
    __syncthreads();

    // scatter register records into bucket-grouped LDS slots
#pragma unroll
    for (int it = 0; it < 2; it++) {
        int nv = nvs[it];
#pragma unroll
        for (int k = 0; k < 4; k++) {
            if (k < nv) {
                int b = rb[it][k];
                int posl = ((b > 0) ? hist[b - 1] : 0) + atomicAdd(&cnt2[b], 1);
                lrec[posl] = make_int2(rx[it][k], rw[it][k]);  // posl < THALF exact
                bkt[posl] = (unsigned short)b;
            }
        }
    }
    __syncthreads();

    // pass C: coalesced segment write-out
    int kc = hist[NBKT - 1];
    for (int i = tid; i < kc; i += 256) {
        int2 rc = lrec[i];
        int b = bkt[i];
        int excl = (b > 0) ? hist[b - 1] : 0;
        int gpos = gbase[b] + (i - excl);
        if (gpos < REG_B)
            recs_g[(size_t)b * REG_B + gpos] = rc;
    }
}

// ---------------------------------------------------------------------------
// K3 (k_aggsort): one block per 64-node bucket (gb*64 = first node).
//     Records -> registers -> histogram by (r.x>>17)&63 = d&63 -> sorted
//     LDS scatter (re-encoded {s<<7, w}). Aggregation: 8 lanes x dwordx4
//     per record, 4 gathers in flight. Epilogue writes h (fp16) into u;
//     k_uv does the dense matvec. At the ~3.2 TB/s random-line ceiling.
// ---------------------------------------------------------------------------
__global__ void __launch_bounds__(256) k_aggsort(
        const int2* __restrict__ recs_g, const int* __restrict__ gcur,
        const float* __restrict__ a_src, const float* __restrict__ a_dst,
        const __half2* __restrict__ xp2, const float* __restrict__ bias,
        __half* __restrict__ hb) {
    __shared__ int2 lrec2[REG_B];        // 14.3 KB (sorted, re-encoded records)
    __shared__ int hist[BKT_NODES];
    __shared__ int incl[BKT_NODES];      // inclusive scan
    __shared__ int cnt2[BKT_NODES];

    int gb = blockIdx.x;
    int node0 = gb * BKT_NODES;
    int nnodes = N_NODES - node0;
    if (nnodes > BKT_NODES) nnodes = BKT_NODES;
    int tid = threadIdx.x;
    int cnt = gcur[gb]; if (cnt > REG_B) cnt = REG_B;
    const int2* breg = recs_g + (size_t)gb * REG_B;

    if (tid < BKT_NODES) { hist[tid] = 0; cnt2[tid] = 0; }
    __syncthreads();

    // load records into registers (coalesced) + histogram by node
    int2 r[NR];
#pragma unroll
    for (int j = 0; j < NR; j++) {
        int i = tid + j * 256;
        if (i < cnt) {
            r[j] = breg[i];
            atomicAdd(&hist[(r[j].x >> 17) & 63], 1);
        }
    }
    __syncthreads();

    // inclusive scan over 64 node counts
    if (tid < BKT_NODES) incl[tid] = hist[tid];
    __syncthreads();
    for (int off = 1; off < BKT_NODES; off <<= 1) {
        int vv = (tid < BKT_NODES && tid >= off) ? incl[tid - off] : 0;
        __syncthreads();
        if (tid < BKT_NODES) incl[tid] += vv;
        __syncthreads();
    }

    // scatter registers into sorted LDS positions, re-encode x -> s*128
    // (byte offset into xp2; s < 2^17 so s<<7 < 2^24)
#pragma unroll
    for (int j = 0; j < NR; j++) {
        int i = tid + j * 256;
        if (i < cnt) {
            int n6 = (r[j].x >> 17) & 63;
            int pos = incl[n6] - hist[n6] + atomicAdd(&cnt2[n6], 1);
            lrec2[pos] = make_int2((r[j].x & 0x1FFFF) << 7, r[j].y);
        }
    }
    __syncthreads();

    int grp = tid >> 5;                  // 32-lane group id (0..7)
    int lane = tid & 31;
    int hlf = lane >> 4;                 // 0 = node A, 1 = node B
    int slot = (lane >> 3) & 1;          // record parity
    int sub = lane & 7;                  // 16B sub-row of the 128B xp2 row
    const char* xpb = (const char*)xp2 + sub * 16;
    const __half2 z2 = __floats2half2_rn(0.f, 0.f);

#pragma unroll
    for (int pi = 0; pi < 4; pi++) {
        int nlA = grp + pi * 16;
        int nlB = nlA + 8;
        int nl = hlf ? nlB : nlA;
        bool valid = nl < nnodes;        // hist[nl]==0 when !valid, reads safe
        int cn = hist[nl];
        int st = incl[nl] - cn;
        int last = (cn > 0) ? cn - 1 : 0;

        // fp32 accumulators: 4 channel-pairs (head0,head1 interleaved) + den
        float an[8] = {0.f, 0.f, 0.f, 0.f, 0.f, 0.f, 0.f, 0.f};
        float ad0 = 0.f, ad1 = 0.f;

        for (int j = 0; j < cn; j += 8) {
            int2 rc[4];
#pragma unroll
            for (int t = 0; t < 4; t++) {
                int idx = j + slot + 2 * t;
                idx = (idx < last) ? idx : last;      // clamp tail (w masked below)
                rc[t] = lrec2[st + idx];              // broadcast across 8 lanes
            }
            int4 xv[4];
#pragma unroll
            for (int t = 0; t < 4; t++)
                xv[t] = *(const int4*)(xpb + rc[t].x);  // 16B/lane, 128B/record
            __half2 nb0 = z2, nb1 = z2, nb2 = z2, nb3 = z2, db = z2;
#pragma unroll
            for (int t = 0; t < 4; t++) {
                int wb = (j + slot + 2 * t < cn) ? rc[t].y : 0;  // mask tail dups
                __half2 w = bits_to_h2(wb);
                const __half2* xh = (const __half2*)&xv[t];
                db = __hadd2(db, w);
                nb0 = __hfma2(w, xh[0], nb0);
                nb1 = __hfma2(w, xh[1], nb1);
                nb2 = __hfma2(w, xh[2], nb2);
                nb3 = __hfma2(w, xh[3], nb3);
            }
            float2 f;
            f = __half22float2(nb0); an[0] += f.x; an[1] += f.y;
            f = __half22float2(nb1); an[2] += f.x; an[3] += f.y;
            f = __half22float2(nb2); an[4] += f.x; an[5] += f.y;
            f = __half22float2(nb3); an[6] += f.x; an[7] += f.y;
            f = __half22float2(db);  ad0 += f.x;  ad1 += f.y;
        }

        // cross-slot reduce (lane ^ 8 stays within the 16-lane half)
#pragma unroll
        for (int q = 0; q < 8; q++) an[q] += __shfl_xor(an[q], 8, 32);
        ad0 += __shfl_xor(ad0, 8, 32);
        ad1 += __shfl_xor(ad1, 8, 32);

        // per-lane epilogue: self-loop + softmax mean -> h for 4 channels,
        // write fp16 h row (8 lanes x 8B = 64B per node, slot 0 only)
        int d = node0 + (valid ? nl : 0);
        float2 Ad = ((const float2*)a_dst)[d];
        float2 As = ((const float2*)a_src)[d];
        float e0 = As.x + Ad.x; e0 = (e0 > 0.f) ? e0 : NEG_SLOPE * e0;
        float e1 = As.y + Ad.y; e1 = (e1 > 0.f) ? e1 : NEG_SLOPE * e1;
        float w00 = __expf(e0), w01 = __expf(e1);
        int4 xsv = *(const int4*)((const char*)xp2 + (size_t)d * 128 + sub * 16);
        const __half2* xs = (const __half2*)&xsv;
        float4 bv = *(const float4*)(bias + sub * 4);
        const float* bvf = (const float*)&bv;
        float den0 = ad0 + w00 + 1e-16f;
        float den1 = ad1 + w01 + 1e-16f;
        float h[4];
#pragma unroll
        for (int t = 0; t < 4; t++) {
            float2 xf = __half22float2(xs[t]);
            float num0 = an[2 * t]     + w00 * xf.x;
            float num1 = an[2 * t + 1] + w01 * xf.y;
            h[t] = 0.5f * (num0 / den0 + num1 / den1) + bvf[t];
        }
        if (valid && slot == 0) {
            __half2 p0 = __floats2half2_rn(h[0], h[1]);
            __half2 p1 = __floats2half2_rn(h[2], h[3]);
            uint2 pk;
            pk.x = *reinterpret_cast<unsigned int*>(&p0);
            pk.y = *reinterpret_cast<unsigned int*>(&p1);
            *reinterpret_cast<uint2*>(hb + (size_t)d * 32 + sub * 4) = pk;
        }
    }
}

// ---------------------------------------------------------------------------
// K3b (k_uv): dense [64,32]x[32,64] per block. Stages w1 (8KB) + h tile
//     (8KB, fp32-converted) in LDS; w1 column held in registers; computes
//     u = h*w1[0:32]+b1 and v = h*w1[32:64] IN-PLACE over the u buffer
//     (h was written there by k_aggsort; per-block tiles are disjoint and
//     all global h reads complete before the first u write -> race-free).
// ---------------------------------------------------------------------------
__global__ void __launch_bounds__(256) k_uv(
        const float* __restrict__ w1, const float* __restrict__ b1,
        __half* __restrict__ u, __half* __restrict__ v) {
    __shared__ float w1s[64 * 32];       // 8 KB
    __shared__ float hs[UV_TILE * 32];   // 8 KB
    int tid = threadIdx.x;
    int n0 = blockIdx.x * UV_TILE;

    // stage w1 (2048 floats, coalesced float4)
#pragma unroll
    for (int q = 0; q < 2; q++) {
        int i = tid + q * 256;
        ((float4*)w1s)[i] = ((const float4*)w1)[i];
    }
    // stage h tile: 4 threads per node row, 8 halves (16B) each -> fp32 LDS
    {
        int nl = tid >> 2;
        int n = n0 + nl;
        float hv[8];
        if (n < N_NODES) {
            uint4 raw = *(const uint4*)(u + (size_t)n * 32 + (tid & 3) * 8);
            const __half2* hp = (const __half2*)&raw;
#pragma unroll
            for (int t = 0; t < 4; t++) {
                float2 f = __half22float2(hp[t]);
                hv[2 * t] = f.x; hv[2 * t + 1] = f.y;
            }
        } else {
#pragma unroll
            for (int t = 0; t < 8; t++) hv[t] = 0.f;
        }
        float* dl = hs + nl * 32 + (tid & 3) * 8;
#pragma unroll
        for (int t = 0; t < 8; t++) dl[t] = hv[t];
    }
    __syncthreads();

    int ch = tid & 31, ng = tid >> 5;
    float wc[64];
#pragma unroll
    for (int c = 0; c < 64; c++) wc[c] = w1s[c * 32 + ch];  // conflict-free
    float bb = b1[ch];

#pragma unroll
    for (int p = 0; p < 8; p++) {
        int nl = p * 8 + ng;
        int n = n0 + nl;
        if (n < N_NODES) {
            const float* hr = hs + nl * 32;   // broadcast reads (2-way max)
            float uu = bb, vv = 0.f;
#pragma unroll
            for (int c = 0; c < 32; c++) {
                float hv = hr[c];
                uu += hv * wc[c];
                vv += hv * wc[32 + c];
            }
            u[(size_t)n * 32 + ch] = __float2half(uu);
            v[(size_t)n * 32 + ch] = __float2half(vv);
        }
    }
}

// ---------------------------------------------------------------------------
// K4: per-edge logits in original edge order (coalesced out writes),
//     2 edges/thread. u/v fp16 rows gathered; packed-half2 dot, fp32 combine.
//     At the ~3.2 TB/s random-line ceiling (155.7 MB / 51.2 us).
// ---------------------------------------------------------------------------
__global__ void k_mlp(const int* __restrict__ src, const int* __restrict__ dst,
                      const __half2* __restrict__ u2, const __half2* __restrict__ v2,
                      const __half2* __restrict__ w2h, const float* __restrict__ b2,
                      float* __restrict__ out) {
    int t = blockIdx.x * blockDim.x + threadIdx.x;
    if (t >= MLP_T) return;
    __half2 wl[16];
#pragma unroll
    for (int q = 0; q < 4; q++) ((float4*)wl)[q] = ((const float4*)w2h)[q];
    int s[MLP_B], d[MLP_B];
#pragma unroll
    for (int k = 0; k < MLP_B; k++) {
        s[k] = src[t + k * MLP_T];
        d[k] = dst[t + k * MLP_T];
    }
    float4 ua[MLP_B][4], va[MLP_B][4];
#pragma unroll
    for (int k = 0; k < MLP_B; k++) {
        const float4* up4 = (const float4*)(u2 + s[k] * 16);
        const float4* vp4 = (const float4*)(v2 + d[k] * 16);
#pragma unroll
        for (int q = 0; q < 4; q++) { ua[k][q] = up4[q]; va[k][q] = vp4[q]; }
    }
#pragma unroll
    for (int k = 0; k < MLP_B; k++) {
        const __half2* uh = (const __half2*)ua[k];
        const __half2* vh = (const __half2*)va[k];
        const __half2 z2 = __floats2half2_rn(0.f, 0.f);
        __half2 acc0 = z2, acc1 = z2, acc2 = z2, acc3 = z2;
#pragma unroll
        for (int q = 0; q < 16; q += 4) {
            acc0 = __hfma2(h2_relu(__hadd2(uh[q + 0], vh[q + 0])), wl[q + 0], acc0);
            acc1 = __hfma2(h2_relu(__hadd2(uh[q + 1], vh[q + 1])), wl[q + 1], acc1);
            acc2 = __hfma2(h2_relu(__hadd2(uh[q + 2], vh[q + 2])), wl[q + 2], acc2);
            acc3 = __hfma2(h2_relu(__hadd2(uh[q + 3], vh[q + 3])), wl[q + 3], acc3);
        }
        float2 f0 = __half22float2(acc0);
        float2 f1 = __half22float2(acc1);
        float2 f2 = __half22float2(acc2);
        float2 f3 = __half22float2(acc3);
        float acc = b2[0] + (f0.x + f0.y) + (f1.x + f1.y) + (f2.x + f2.y) + (f3.x + f3.y);
        out[t + k * MLP_T] = acc * INV_TEMP;
    }
}

// ---------------------------------------------------------------------------
extern "C" void kernel_launch(void* const* d_in, const int* in_sizes, int n_in,
                              void* d_out, int out_size, void* d_ws, size_t ws_size,
                              hipStream_t stream) {
    const float* x       = (const float*)d_in[0];
    const int*   eidx    = (const int*)d_in[1];          // [2,E] int32
    const float* W       = (const float*)d_in[2];
    const float* att_src = (const float*)d_in[3];
    const float* att_dst = (const float*)d_in[4];
    const float* bias    = (const float*)d_in[5];
    const float* w1      = (const float*)d_in[6];
    const float* b1      = (const float*)d_in[7];
    const float* w2      = (const float*)d_in[8];
    const float* b2      = (const float*)d_in[9];
    float* out = (float*)d_out;

    const int* src = eidx;             // row 0
    const int* dst = eidx + E_EDGES;   // row 1

    // Workspace layout: see OFF_* constexprs (all 128B-aligned, ~47.3 MB).
    char* base = (char*)d_ws;
    int* gcur     = (int*)base;
    __half2* w2h  = (__half2*)(base + OFF_W2H);
    int2* recs_g  = (int2*)(base + OFF_RECS);
    float* a_src  = (float*)(base + OFF_ASRC);
    float* a_dst  = (float*)(base + OFF_ADST);
    __half2* xp2  = (__half2*)(base + OFF_XP2);
    __half* u     = (__half*)(base + OFF_U);
    __half* v     = (__half*)(base + OFF_V);

    constexpr int BS = 256;

    // K1: node transform (+ gcur zero + w2 pack, fused)
    k_node<<<(N_NODES + BS - 1) / BS, BS, 0, stream>>>(x, W, att_src, att_dst,
                                                      xp2, a_src, a_dst, gcur, w2, w2h);

    // K2: single-sweep register-held LDS counting sort (grid 782)
    k_split<<<NTH, BS, 0, stream>>>(src, dst, a_src, a_dst, gcur, recs_g);

    // K3: per-bucket aggregation (64-node buckets, grid 1563); writes h -> u
    k_aggsort<<<NBKT, BS, 0, stream>>>(recs_g, gcur, a_src, a_dst, xp2, bias, u);

    // K3b: dense u/v matvec (in-place over u, writes v)
    k_uv<<<UV_GRID, BS, 0, stream>>>(w1, b1, u, v);

    // K4: per-edge logits (edge order, 2 edges/thread)
    k_mlp<<<(MLP_T + BS - 1) / BS, BS, 0, stream>>>(src, dst, (const __half2*)u,
                                                   (const __half2*)v, w2h, b2, out);
}

// Round 12
// 226.041 us; speedup vs baseline: 1.1163x; 1.1163x over previous
//
#include <hip/hip_runtime.h>
#include <hip/hip_fp16.h>
#include <cstdint>

// Problem constants (match reference)
constexpr int N_NODES = 100000;
constexpr int E_EDGES = 1600000;
constexpr float NEG_SLOPE = 0.2f;
constexpr float INV_TEMP = 1.0f / 0.7f;

// Bucket geometry (global 64-node buckets; record {s | (d&63)<<17, w},
// bucket id d>>6 carried in a side ushort array).
constexpr int BKT_NODES = 64;
constexpr int NBKT = (N_NODES + BKT_NODES - 1) / BKT_NODES;  // 1563
constexpr int REG_B = 1792;                      // recs per bucket (mean 1024, +24 sigma)
constexpr int NR = REG_B / 256;                  // 7 recs held per thread
constexpr int THALF = 4096;                      // R12: reverted to R10's measured-best
constexpr int NTH = (E_EDGES + THALF - 1) / THALF;  // 391
constexpr int HBINS = 1792;                      // 7*256 scan bins (1563 used)

constexpr int MLP_B = 2;
constexpr int MLP_T = E_EDGES / MLP_B;           // 800000

// Workspace offsets -- ALL 128B-aligned (R9 lesson: cacheline-phase shifts
// from geometry changes cost k_mlp 1.5x FETCH; statically pinned since).
constexpr size_t OFF_W2H  = 6272;                               // gcur: NBKT*4=6252
constexpr size_t OFF_RECS = 6400;
constexpr size_t OFF_ASRC = OFF_RECS + (size_t)NBKT * REG_B * 8;  // +22,407,168
constexpr size_t OFF_ADST = OFF_ASRC + 800000;
constexpr size_t OFF_XP2  = OFF_ADST + 800000;
constexpr size_t OFF_U    = OFF_XP2 + 12800000;
constexpr size_t OFF_V    = OFF_U + 6400000;
static_assert(OFF_RECS % 128 == 0 && OFF_ASRC % 128 == 0 && OFF_XP2 % 128 == 0 &&
              OFF_U % 128 == 0 && OFF_V % 128 == 0, "alignment");
static_assert((size_t)NBKT * 4 <= OFF_W2H, "gcur overlap");

__device__ __forceinline__ __half2 bits_to_h2(int bits) {
    return *reinterpret_cast<__half2*>(&bits);
}

// packed relu (no __hmax2 in ROCm 7.2 headers; __hgt2 gives packed 1/0 mask)
__device__ __forceinline__ __half2 h2_relu(__half2 a) {
    const __half2 z = __floats2half2_rn(0.f, 0.f);
    return __hmul2(a, __hgt2(a, z));
}

// ---------------------------------------------------------------------------
// K1: per-node transform. xp2[n][c] = half2(head0_c, head1_c); a_src/a_dst
//     dots [N,2] fp32. Fused: zero gcur[1563], pack w2 -> w2h[16].
// ---------------------------------------------------------------------------
__global__ void k_node(const float* __restrict__ x, const float* __restrict__ W,
                       const float* __restrict__ att_src, const float* __restrict__ att_dst,
                       __half2* __restrict__ xp2, float* __restrict__ a_src,
                       float* __restrict__ a_dst, int* __restrict__ gcur,
                       const float* __restrict__ w2, __half2* __restrict__ w2h) {
    int n = blockIdx.x * blockDim.x + threadIdx.x;
    if (blockIdx.x == 0 && threadIdx.x < 16)
        w2h[threadIdx.x] = __floats2half2_rn(w2[2 * threadIdx.x], w2[2 * threadIdx.x + 1]);
    if (n < NBKT) gcur[n] = 0;
    if (n >= N_NODES) return;
    float xi[16];
    const float4* xv = (const float4*)(x + (size_t)n * 16);
    ((float4*)xi)[0] = xv[0];
    ((float4*)xi)[1] = xv[1];
    ((float4*)xi)[2] = xv[2];
    ((float4*)xi)[3] = xv[3];
    float as0 = 0.f, as1 = 0.f, ad0 = 0.f, ad1 = 0.f;
    __half2 hbuf[32];
#pragma unroll
    for (int c = 0; c < 32; c++) {
        float acc0 = 0.f, acc1 = 0.f;
#pragma unroll
        for (int k = 0; k < 16; k++) {
            acc0 += xi[k] * W[k * 64 + c];
            acc1 += xi[k] * W[k * 64 + 32 + c];
        }
        hbuf[c] = __floats2half2_rn(acc0, acc1);
        as0 += acc0 * att_src[c];
        as1 += acc1 * att_src[32 + c];
        ad0 += acc0 * att_dst[c];
        ad1 += acc1 * att_dst[32 + c];
    }
    float4* dst4 = (float4*)(xp2 + (size_t)n * 32);
#pragma unroll
    for (int q = 0; q < 8; q++) dst4[q] = ((float4*)hbuf)[q];
    ((float2*)a_src)[n] = make_float2(as0, as1);
    ((float2*)a_dst)[n] = make_float2(ad0, ad1);
}

// ---------------------------------------------------------------------------
// K2 (k_split): R10's measured version (44 us). One block per 4096-edge
//     tile; two-pass LDS counting sort; bucket = d>>6 (one shift).
//     R11's single-sweep @2048 regressed to 65 us: doubling the block
//     count doubled the gcur global-atomic count (~860K atomics on 98
//     cachelines -- all pipes <10% busy, pure serialization). Reverted.
// ---------------------------------------------------------------------------
__global__ void __launch_bounds__(256) k_split(
        const int* __restrict__ src, const int* __restrict__ dst,
        const float* __restrict__ a_src, const float* __restrict__ a_dst,
        int* __restrict__ gcur, int2* __restrict__ recs_g) {
    __shared__ int2 lrec[THALF];            // 32 KB
    __shared__ unsigned short bkt[THALF];   // 8 KB
    __shared__ int hist[HBINS];             // 7 KB (becomes inclusive scan)
    __shared__ int psum[256];               // 1 KB
    __shared__ int cnt2[NBKT];              // 6.25 KB
    __shared__ int gbase[NBKT];             // 6.25 KB

    int th = blockIdx.x;
    int tid = threadIdx.x;
    int ebase = th * THALF;

    for (int b = tid; b < HBINS; b += 256) hist[b] = 0;
    for (int b = tid; b < NBKT; b += 256) cnt2[b] = 0;
    __syncthreads();

    // pass A: histogram by d>>6
#pragma unroll
    for (int it = 0; it < THALF / (256 * 4); it++) {
        int e4 = ebase + (it * 256 + tid) * 4;
        if (e4 + 3 < E_EDGES) {
            int4 d4 = *(const int4*)(dst + e4);
            atomicAdd(&hist[d4.x >> 6], 1);
            atomicAdd(&hist[d4.y >> 6], 1);
            atomicAdd(&hist[d4.z >> 6], 1);
            atomicAdd(&hist[d4.w >> 6], 1);
        } else if (e4 < E_EDGES) {
            int nv = E_EDGES - e4;
            for (int k = 0; k < nv; k++) atomicAdd(&hist[dst[e4 + k] >> 6], 1);
        }
    }
    __syncthreads();

    // blocked inclusive scan over HBINS bins, 7 bins/thread, in place
    int loc[7];
    int tsum = 0;
#pragma unroll
    for (int k = 0; k < 7; k++) { loc[k] = hist[tid * 7 + k]; tsum += loc[k]; }
    psum[tid] = tsum;
    __syncthreads();
    for (int off = 1; off < 256; off <<= 1) {
        int v = (tid >= off) ? psum[tid - off] : 0;
        __syncthreads();
        psum[tid] += v;
        __syncthreads();
    }
    {
        int run = psum[tid] - tsum;          // exclusive prefix of this thread
#pragma unroll
        for (int k = 0; k < 7; k++) { run += loc[k]; hist[tid * 7 + k] = run; }
    }
    __syncthreads();

    // reserve global space (count = incl[b] - incl[b-1])
    for (int b = tid; b < NBKT; b += 256) {
        int c = hist[b] - ((b > 0) ? hist[b - 1] : 0);
        gbase[b] = atomicAdd(&gcur[b], c);
    }
    __syncthreads();

    // pass B: compute weights, place into bucket-grouped LDS slots
#pragma unroll
    for (int it = 0; it < THALF / (256 * 4); it++) {
        int e4 = ebase + (it * 256 + tid) * 4;
        int dd[4], ss[4], nv = 0;
        if (e4 + 3 < E_EDGES) {
            int4 d4 = *(const int4*)(dst + e4);
            int4 s4 = *(const int4*)(src + e4);
            dd[0] = d4.x; dd[1] = d4.y; dd[2] = d4.z; dd[3] = d4.w;
            ss[0] = s4.x; ss[1] = s4.y; ss[2] = s4.z; ss[3] = s4.w;
            nv = 4;
        } else if (e4 < E_EDGES) {
            nv = E_EDGES - e4;
            for (int k = 0; k < nv; k++) { dd[k] = dst[e4 + k]; ss[k] = src[e4 + k]; }
        }
        for (int k = 0; k < nv; k++) {
            int d = dd[k], s = ss[k];
            float2 As = ((const float2*)a_src)[s];
            float2 Ad = ((const float2*)a_dst)[d];
            float e0 = As.x + Ad.x; e0 = (e0 > 0.f) ? e0 : NEG_SLOPE * e0;
            float e1 = As.y + Ad.y; e1 = (e1 > 0.f) ? e1 : NEG_SLOPE * e1;
            __half2 hw = __floats2half2_rn(__expf(e0), __expf(e1));
            int wb = *reinterpret_cast<int*>(&hw);
            int b = d >> 6;
            int posl = ((b > 0) ? hist[b - 1] : 0) + atomicAdd(&cnt2[b], 1);
            lrec[posl] = make_int2(s | ((d & 63) << 17), wb);  // posl < THALF exact
            bkt[posl] = (unsigned short)b;
        }
    }
    __syncthreads();

    // pass C: coalesced segment write-out
    int kc = hist[NBKT - 1];
    for (int i = tid; i < kc; i += 256) {
        int2 rc = lrec[i];
        int b = bkt[i];
        int excl = (b > 0) ? hist[b - 1] : 0;
        int gpos = gbase[b] + (i - excl);
        if (gpos < REG_B)
            recs_g[(size_t)b * REG_B + gpos] = rc;
    }
}

// ---------------------------------------------------------------------------
// K3 (k_aggsort) R12: k_uv FUSED into the epilogue. Each block already
//     computes h for exactly the 64 nodes k_uv would tile, so: h rows are
//     collected fp32 in LDS (no fp16 round-trip through global), then the
//     dense [64,32]x[32,64] matvec runs in-block with w1 staged in LDS,
//     writing u and v directly. Saves one kernel launch (+gap) and the
//     12.8 MB h write+read. LDS 31 KB.
// ---------------------------------------------------------------------------
__global__ void __launch_bounds__(256) k_aggsort(
        const int2* __restrict__ recs_g, const int* __restrict__ gcur,
        const float* __restrict__ a_src, const float* __restrict__ a_dst,
        const __half2* __restrict__ xp2, const float* __restrict__ bias,
        const float* __restrict__ w1, const float* __restrict__ b1,
        __half* __restrict__ u, __half* __restrict__ v) {
    __shared__ int2 lrec2[REG_B];        // 14.3 KB (sorted, re-encoded records)
    __shared__ float w1s[64 * 32];       // 8 KB
    __shared__ float hs[BKT_NODES * 32]; // 8 KB (fp32 h tile)
    __shared__ int hist[BKT_NODES];
    __shared__ int incl[BKT_NODES];      // inclusive scan
    __shared__ int cnt2[BKT_NODES];

    int gb = blockIdx.x;
    int node0 = gb * BKT_NODES;
    int nnodes = N_NODES - node0;
    if (nnodes > BKT_NODES) nnodes = BKT_NODES;
    int tid = threadIdx.x;
    int cnt = gcur[gb]; if (cnt > REG_B) cnt = REG_B;
    const int2* breg = recs_g + (size_t)gb * REG_B;

    // stage w1 (2048 floats, coalesced float4)
#pragma unroll
    for (int q = 0; q < 2; q++) {
        int i = tid + q * 256;
        ((float4*)w1s)[i] = ((const float4*)w1)[i];
    }
    if (tid < BKT_NODES) { hist[tid] = 0; cnt2[tid] = 0; }
    __syncthreads();

    // load records into registers (coalesced) + histogram by node
    int2 r[NR];
#pragma unroll
    for (int j = 0; j < NR; j++) {
        int i = tid + j * 256;
        if (i < cnt) {
            r[j] = breg[i];
            atomicAdd(&hist[(r[j].x >> 17) & 63], 1);
        }
    }
    __syncthreads();

    // inclusive scan over 64 node counts
    if (tid < BKT_NODES) incl[tid] = hist[tid];
    __syncthreads();
    for (int off = 1; off < BKT_NODES; off <<= 1) {
        int vv = (tid < BKT_NODES && tid >= off) ? incl[tid - off] : 0;
        __syncthreads();
        if (tid < BKT_NODES) incl[tid] += vv;
        __syncthreads();
    }

    // scatter registers into sorted LDS positions, re-encode x -> s*128
    // (byte offset into xp2; s < 2^17 so s<<7 < 2^24)
#pragma unroll
    for (int j = 0; j < NR; j++) {
        int i = tid + j * 256;
        if (i < cnt) {
            int n6 = (r[j].x >> 17) & 63;
            int pos = incl[n6] - hist[n6] + atomicAdd(&cnt2[n6], 1);
            lrec2[pos] = make_int2((r[j].x & 0x1FFFF) << 7, r[j].y);
        }
    }
    __syncthreads();

    int grp = tid >> 5;                  // 32-lane group id (0..7)
    int lane = tid & 31;
    int hlf = lane >> 4;                 // 0 = node A, 1 = node B
    int slot = (lane >> 3) & 1;          // record parity
    int sub = lane & 7;                  // 16B sub-row of the 128B xp2 row
    const char* xpb = (const char*)xp2 + sub * 16;
    const __half2 z2 = __floats2half2_rn(0.f, 0.f);

#pragma unroll
    for (int pi = 0; pi < 4; pi++) {
        int nlA = grp + pi * 16;
        int nlB = nlA + 8;
        int nl = hlf ? nlB : nlA;
        bool valid = nl < nnodes;        // hist[nl]==0 when !valid, reads safe
        int cn = hist[nl];
        int st = incl[nl] - cn;
        int last = (cn > 0) ? cn - 1 : 0;

        // fp32 accumulators: 4 channel-pairs (head0,head1 interleaved) + den
        float an[8] = {0.f, 0.f, 0.f, 0.f, 0.f, 0.f, 0.f, 0.f};
        float ad0 = 0.f, ad1 = 0.f;

        for (int j = 0; j < cn; j += 8) {
            int2 rc[4];
#pragma unroll
            for (int t = 0; t < 4; t++) {
                int idx = j + slot + 2 * t;
                idx = (idx < last) ? idx : last;      // clamp tail (w masked below)
                rc[t] = lrec2[st + idx];              // broadcast across 8 lanes
            }
            int4 xv[4];
#pragma unroll
            for (int t = 0; t < 4; t++)
                xv[t] = *(const int4*)(xpb + rc[t].x);  // 16B/lane, 128B/record
            __half2 nb0 = z2, nb1 = z2, nb2 = z2, nb3 = z2, db = z2;
#pragma unroll
            for (int t = 0; t < 4; t++) {
                int wb = (j + slot + 2 * t < cn) ? rc[t].y : 0;  // mask tail dups
                __half2 w = bits_to_h2(wb);
                const __half2* xh = (const __half2*)&xv[t];
                db = __hadd2(db, w);
                nb0 = __hfma2(w, xh[0], nb0);
                nb1 = __hfma2(w, xh[1], nb1);
                nb2 = __hfma2(w, xh[2], nb2);
                nb3 = __hfma2(w, xh[3], nb3);
            }
            float2 f;
            f = __half22float2(nb0); an[0] += f.x; an[1] += f.y;
            f = __half22float2(nb1); an[2] += f.x; an[3] += f.y;
            f = __half22float2(nb2); an[4] += f.x; an[5] += f.y;
            f = __half22float2(nb3); an[6] += f.x; an[7] += f.y;
            f = __half22float2(db);  ad0 += f.x;  ad1 += f.y;
        }

        // cross-slot reduce (lane ^ 8 stays within the 16-lane half)
#pragma unroll
        for (int q = 0; q < 8; q++) an[q] += __shfl_xor(an[q], 8, 32);
        ad0 += __shfl_xor(ad0, 8, 32);
        ad1 += __shfl_xor(ad1, 8, 32);

        // per-lane epilogue: self-loop + softmax mean -> h for 4 channels,
        // collected fp32 into LDS hs (slot 0 lanes: 8 x 16B per node)
        int d = node0 + (valid ? nl : 0);
        float2 Ad = ((const float2*)a_dst)[d];
        float2 As = ((const float2*)a_src)[d];
        float e0 = As.x + Ad.x; e0 = (e0 > 0.f) ? e0 : NEG_SLOPE * e0;
        float e1 = As.y + Ad.y; e1 = (e1 > 0.f) ? e1 : NEG_SLOPE * e1;
        float w00 = __expf(e0), w01 = __expf(e1);
        int4 xsv = *(const int4*)((const char*)xp2 + (size_t)d * 128 + sub * 16);
        const __half2* xs = (const __half2*)&xsv;
        float4 bv = *(const float4*)(bias + sub * 4);
        const float* bvf = (const float*)&bv;
        float den0 = ad0 + w00 + 1e-16f;
        float den1 = ad1 + w01 + 1e-16f;
        if (valid && slot == 0) {
            float* hr = hs + nl * 32 + sub * 4;
#pragma unroll
            for (int t = 0; t < 4; t++) {
                float2 xf = __half22float2(xs[t]);
                float num0 = an[2 * t]     + w00 * xf.x;
                float num1 = an[2 * t + 1] + w01 * xf.y;
                hr[t] = 0.5f * (num0 / den0 + num1 / den1) + bvf[t];
            }
        }
    }
    __syncthreads();

    // fused k_uv: dense [64,32]x[32,64] matvec; u = h*w1[0:32]+b1,
    // v = h*w1[32:64] (identical math to the old k_uv kernel)
    int ch = tid & 31, ng = tid >> 5;
    float wc[64];
#pragma unroll
    for (int c = 0; c < 64; c++) wc[c] = w1s[c * 32 + ch];  // conflict-free
    float bb = b1[ch];

#pragma unroll
    for (int p = 0; p < 8; p++) {
        int nl = p * 8 + ng;
        int n = node0 + nl;
        if (nl < nnodes) {
            const float* hr = hs + nl * 32;   // broadcast reads
            float uu = bb, vv = 0.f;
#pragma unroll
            for (int c = 0; c < 32; c++) {
                float hv = hr[c];
                uu += hv * wc[c];
                vv += hv * wc[32 + c];
            }
            u[(size_t)n * 32 + ch] = __float2half(uu);
            v[(size_t)n * 32 + ch] = __float2half(vv);
        }
    }
}

// ---------------------------------------------------------------------------
// K4: per-edge logits in original edge order (coalesced out writes),
//     2 edges/thread. u/v fp16 rows gathered; packed-half2 dot, fp32 combine.
//     At the ~3.2 TB/s random-line ceiling (155.7 MB / 51.2 us).
// ---------------------------------------------------------------------------
__global__ void k_mlp(const int* __restrict__ src, const int* __restrict__ dst,
                      const __half2* __restrict__ u2, const __half2* __restrict__ v2,
                      const __half2* __restrict__ w2h, const float* __restrict__ b2,
                      float* __restrict__ out) {
    int t = blockIdx.x * blockDim.x + threadIdx.x;
    if (t >= MLP_T) return;
    __half2 wl[16];
#pragma unroll
    for (int q = 0; q < 4; q++) ((float4*)wl)[q] = ((const float4*)w2h)[q];
    int s[MLP_B], d[MLP_B];
#pragma unroll
    for (int k = 0; k < MLP_B; k++) {
        s[k] = src[t + k * MLP_T];
        d[k] = dst[t + k * MLP_T];
    }
    float4 ua[MLP_B][4], va[MLP_B][4];
#pragma unroll
    for (int k = 0; k < MLP_B; k++) {
        const float4* up4 = (const float4*)(u2 + s[k] * 16);
        const float4* vp4 = (const float4*)(v2 + d[k] * 16);
#pragma unroll
        for (int q = 0; q < 4; q++) { ua[k][q] = up4[q]; va[k][q] = vp4[q]; }
    }
#pragma unroll
    for (int k = 0; k < MLP_B; k++) {
        const __half2* uh = (const __half2*)ua[k];
        const __half2* vh = (const __half2*)va[k];
        const __half2 z2 = __floats2half2_rn(0.f, 0.f);
        __half2 acc0 = z2, acc1 = z2, acc2 = z2, acc3 = z2;
#pragma unroll
        for (int q = 0; q < 16; q += 4) {
            acc0 = __hfma2(h2_relu(__hadd2(uh[q + 0], vh[q + 0])), wl[q + 0], acc0);
            acc1 = __hfma2(h2_relu(__hadd2(uh[q + 1], vh[q + 1])), wl[q + 1], acc1);
            acc2 = __hfma2(h2_relu(__hadd2(uh[q + 2], vh[q + 2])), wl[q + 2], acc2);
            acc3 = __hfma2(h2_relu(__hadd2(uh[q + 3], vh[q + 3])), wl[q + 3], acc3);
        }
        float2 f0 = __half22float2(acc0);
        float2 f1 = __half22float2(acc1);
        float2 f2 = __half22float2(acc2);
        float2 f3 = __half22float2(acc3);
        float acc = b2[0] + (f0.x + f0.y) + (f1.x + f1.y) + (f2.x + f2.y) + (f3.x + f3.y);
        out[t + k * MLP_T] = acc * INV_TEMP;
    }
}

// ---------------------------------------------------------------------------
extern "C" void kernel_launch(void* const* d_in, const int* in_sizes, int n_in,
                              void* d_out, int out_size, void* d_ws, size_t ws_size,
                              hipStream_t stream) {
    const float* x       = (const float*)d_in[0];
    const int*   eidx    = (const int*)d_in[1];          // [2,E] int32
    const float* W       = (const float*)d_in[2];
    const float* att_src = (const float*)d_in[3];
    const float* att_dst = (const float*)d_in[4];
    const float* bias    = (const float*)d_in[5];
    const float* w1      = (const float*)d_in[6];
    const float* b1      = (const float*)d_in[7];
    const float* w2      = (const float*)d_in[8];
    const float* b2      = (const float*)d_in[9];
    float* out = (float*)d_out;

    const int* src = eidx;             // row 0
    const int* dst = eidx + E_EDGES;   // row 1

    // Workspace layout: see OFF_* constexprs (all 128B-aligned, ~47.3 MB).
    char* base = (char*)d_ws;
    int* gcur     = (int*)base;
    __half2* w2h  = (__half2*)(base + OFF_W2H);
    int2* recs_g  = (int2*)(base + OFF_RECS);
    float* a_src  = (float*)(base + OFF_ASRC);
    float* a_dst  = (float*)(base + OFF_ADST);
    __half2* xp2  = (__half2*)(base + OFF_XP2);
    __half* u     = (__half*)(base + OFF_U);
    __half* v     = (__half*)(base + OFF_V);

    constexpr int BS = 256;

    // K1: node transform (+ gcur zero + w2 pack, fused)
    k_node<<<(N_NODES + BS - 1) / BS, BS, 0, stream>>>(x, W, att_src, att_dst,
                                                      xp2, a_src, a_dst, gcur, w2, w2h);

    // K2: two-pass LDS counting sort -> bucketed records (grid 391, R10 form)
    k_split<<<NTH, BS, 0, stream>>>(src, dst, a_src, a_dst, gcur, recs_g);

    // K3: per-bucket aggregation + fused u/v matvec (grid 1563)
    k_aggsort<<<NBKT, BS, 0, stream>>>(recs_g, gcur, a_src, a_dst, xp2, bias,
                                       w1, b1, u, v);

    // K4: per-edge logits (edge order, 2 edges/thread)
    k_mlp<<<(MLP_T + BS - 1) / BS, BS, 0, stream>>>(src, dst, (const __half2*)u,
                                                   (const __half2*)v, w2h, b2, out);
}